// Round 1
// baseline (228.337 us; speedup 1.0000x reference)
//
#include <hip/hip_runtime.h>

#define TEMP 10.0f
#define NS 4096   // N_star / N_from
#define BB 512    // batch
#define DDIM 512  // feature dim
#define NCLS 10   // classes

// ---------------- init: zero accumulators, sentinel match_idx ----------------
__global__ void init_kernel(float* cs1, float* sumE, float* cs2,
                            float* ynum, float* ydenom, int* midx) {
    int t = blockIdx.x * 256 + threadIdx.x;
    if (t < BB) { cs1[t] = 0.f; sumE[t] = 0.f; cs2[t] = 0.f; ydenom[t] = 0.f; midx[t] = NS; }
    if (t < BB * NCLS) ynum[t] = 0.f;
}

// ---------------- row squared norms (one wave per row of 512 floats) ----------------
__global__ __launch_bounds__(64)
void row_sqnorm(const float* __restrict__ A, float* __restrict__ out) {
    int row = blockIdx.x;
    int lane = threadIdx.x;
    const float4* r = (const float4*)(A + (size_t)row * DDIM);
    float4 a = r[lane];
    float4 b = r[lane + 64];
    float s = a.x*a.x + a.y*a.y + a.z*a.z + a.w*a.w
            + b.x*b.x + b.y*b.y + b.z*b.z + b.w*b.w;
    #pragma unroll
    for (int off = 32; off > 0; off >>= 1) s += __shfl_down(s, off, 64);
    if (lane == 0) out[row] = s;
}

// ---------------- exact-match lookup (first matching star row per x row) ----------------
__global__ void match_kernel(const float* __restrict__ x, const float* __restrict__ star,
                             int* __restrict__ midx) {
    int i = blockIdx.x * blockDim.x + threadIdx.x;  // b inner, n outer
    if (i >= NS * BB) return;
    int b = i & (BB - 1);
    int n = i >> 9;
    const float* xr = x + (size_t)b * DDIM;
    const float* sr = star + (size_t)n * DDIM;
    if (xr[0] != sr[0]) return;          // overwhelmingly-common fast exit
    for (int k = 1; k < DDIM; ++k) if (xr[k] != sr[k]) return;
    atomicMin(&midx[b], n);
}

// ---------------- GEMM  C[m][n] = max(an2[m]+bn2[n]-2*dot(A[m,:],B[n,:]),0)  ----------------
// A: [M,512] row-major, B: [512,512] row-major. Also accumulates column sums of C.
__global__ __launch_bounds__(256)
void gemm_abt_sq(const float* __restrict__ A, const float* __restrict__ Bm,
                 const float* __restrict__ an2, const float* __restrict__ bn2,
                 float* __restrict__ C, float* __restrict__ colsum) {
    __shared__ float As[32][68];   // [k][m], padded: rows 16B-aligned
    __shared__ float Bs[32][68];   // [k][n]
    __shared__ float red[16][65];
    const int K = DDIM;
    int m0 = blockIdx.x * 64, n0 = blockIdx.y * 64;
    int t = threadIdx.x;
    int tx = t & 15, ty = t >> 4;
    float acc[4][4] = {};
    for (int k0 = 0; k0 < K; k0 += 32) {
        int r  = t >> 2;
        int kq = (t & 3) * 8;
        const float* pa = A + (size_t)(m0 + r) * K + k0 + kq;
        float4 a0 = *(const float4*)pa;
        float4 a1 = *(const float4*)(pa + 4);
        As[kq+0][r] = a0.x; As[kq+1][r] = a0.y; As[kq+2][r] = a0.z; As[kq+3][r] = a0.w;
        As[kq+4][r] = a1.x; As[kq+5][r] = a1.y; As[kq+6][r] = a1.z; As[kq+7][r] = a1.w;
        const float* pb = Bm + (size_t)(n0 + r) * K + k0 + kq;
        float4 b0 = *(const float4*)pb;
        float4 b1 = *(const float4*)(pb + 4);
        Bs[kq+0][r] = b0.x; Bs[kq+1][r] = b0.y; Bs[kq+2][r] = b0.z; Bs[kq+3][r] = b0.w;
        Bs[kq+4][r] = b1.x; Bs[kq+5][r] = b1.y; Bs[kq+6][r] = b1.z; Bs[kq+7][r] = b1.w;
        __syncthreads();
        #pragma unroll
        for (int kk = 0; kk < 32; ++kk) {
            float av[4], bv[4];
            *(float4*)av = *(const float4*)&As[kk][ty * 4];
            *(float4*)bv = *(const float4*)&Bs[kk][tx * 4];
            #pragma unroll
            for (int i = 0; i < 4; ++i)
                #pragma unroll
                for (int j = 0; j < 4; ++j)
                    acc[i][j] += av[i] * bv[j];
        }
        __syncthreads();
    }
    float csum[4] = {0.f, 0.f, 0.f, 0.f};
    #pragma unroll
    for (int i = 0; i < 4; ++i) {
        int m = m0 + ty * 4 + i;
        float a2 = an2[m];
        #pragma unroll
        for (int j = 0; j < 4; ++j) {
            int n = n0 + tx * 4 + j;
            float v = fmaxf(a2 + bn2[n] - 2.0f * acc[i][j], 0.0f);
            C[(size_t)m * BB + n] = v;
            csum[j] += v;
        }
    }
    #pragma unroll
    for (int j = 0; j < 4; ++j) red[ty][tx * 4 + j] = csum[j];
    __syncthreads();
    if (ty == 0) {
        #pragma unroll
        for (int j = 0; j < 4; ++j) {
            int c = tx * 4 + j;
            float s = 0.f;
            #pragma unroll
            for (int q = 0; q < 16; ++q) s += red[q][c];
            atomicAdd(&colsum[n0 + c], s);
        }
    }
}

// ---------------- e = exp(-10 * d / colmean), in place; column sums of e ----------------
__global__ __launch_bounds__(256)
void exp_kernel(float* __restrict__ d, const float* __restrict__ cs1,
                float* __restrict__ sumE) {
    int l = threadIdx.x & 63;
    int c = blockIdx.x * 64 + l;
    int rg = threadIdx.x >> 6;           // 0..3
    int row0 = blockIdx.y * 512;
    float inv = -TEMP * (float)NS / cs1[c];
    float s = 0.f;
    for (int n = row0 + rg; n < row0 + 512; n += 4) {
        size_t idx = (size_t)n * BB + c;
        float e = __expf(d[idx] * inv);
        d[idx] = e;
        s += e;
    }
    __shared__ float red[4][64];
    red[rg][l] = s;
    __syncthreads();
    if (rg == 0) {
        float tot = red[0][l] + red[1][l] + red[2][l] + red[3][l];
        atomicAdd(&sumE[c], tot);
    }
}

// ---------------- GEMM  Cpart[s][m][n] = sum_{k in slab s} A[k][m]*B[k][n] ----------------
// A = from_features [4096,512] used transposed, B = e [4096,512].
__global__ __launch_bounds__(256)
void gemm_atb_part(const float* __restrict__ A, const float* __restrict__ Bm,
                   float* __restrict__ Cpart) {
    __shared__ float As[32][68];
    __shared__ float Bs[32][68];
    int m0 = blockIdx.x * 64, n0 = blockIdx.y * 64;
    int kbase = blockIdx.z * 512;
    int t = threadIdx.x;
    int tx = t & 15, ty = t >> 4;
    float acc[4][4] = {};
    for (int k0 = kbase; k0 < kbase + 512; k0 += 32) {
        int k  = t >> 3;
        int mq = (t & 7) * 8;
        const float* pa = A + (size_t)(k0 + k) * DDIM + m0 + mq;
        *(float4*)&As[k][mq]     = *(const float4*)pa;
        *(float4*)&As[k][mq + 4] = *(const float4*)(pa + 4);
        const float* pb = Bm + (size_t)(k0 + k) * BB + n0 + mq;
        *(float4*)&Bs[k][mq]     = *(const float4*)pb;
        *(float4*)&Bs[k][mq + 4] = *(const float4*)(pb + 4);
        __syncthreads();
        #pragma unroll
        for (int kk = 0; kk < 32; ++kk) {
            float av[4], bv[4];
            *(float4*)av = *(const float4*)&As[kk][ty * 4];
            *(float4*)bv = *(const float4*)&Bs[kk][tx * 4];
            #pragma unroll
            for (int i = 0; i < 4; ++i)
                #pragma unroll
                for (int j = 0; j < 4; ++j)
                    acc[i][j] += av[i] * bv[j];
        }
        __syncthreads();
    }
    float* Co = Cpart + (size_t)blockIdx.z * (DDIM * BB);
    #pragma unroll
    for (int i = 0; i < 4; ++i)
        #pragma unroll
        for (int j = 0; j < 4; ++j)
            Co[(size_t)(m0 + ty * 4 + i) * BB + n0 + tx * 4 + j] = acc[i][j];
}

// ---------------- xt[b][d] = (sum_s wpart[s][d][b]) / sumE[b], or matched row ----------------
__global__ void xt_kernel(const float* __restrict__ wpart, const float* __restrict__ sumE,
                          const int* __restrict__ midx, const float* __restrict__ from,
                          float* __restrict__ xt) {
    int i = blockIdx.x * blockDim.x + threadIdx.x;   // i = d*512 + b (coalesced partial reads)
    if (i >= DDIM * BB) return;
    int b = i & (BB - 1), dd = i >> 9;
    float s = 0.f;
    #pragma unroll
    for (int sl = 0; sl < 8; ++sl) s += wpart[(size_t)sl * (DDIM * BB) + i];
    float v = s / sumE[b];
    int mi = midx[b];
    if (mi < NS) v = from[(size_t)mi * DDIM + dd];
    xt[(size_t)b * DDIM + dd] = v;
}

// ---------------- label-weighted average: ynum[b][c], ydenom[b] ----------------
__global__ __launch_bounds__(256)
void ystar_partial(const float* __restrict__ d2, const float* __restrict__ cs2,
                   const int* __restrict__ labels,
                   float* __restrict__ ynum, float* __restrict__ ydenom) {
    int l = threadIdx.x & 63;
    int c = blockIdx.x * 64 + l;         // batch column
    int rg = threadIdx.x >> 6;           // 0..3
    int row0 = blockIdx.y * 512;
    float inv = -TEMP * (float)NS / cs2[c];
    float accs[NCLS] = {};
    float tot = 0.f;
    for (int n = row0 + rg; n < row0 + 512; n += 4) {
        float e = __expf(d2[(size_t)n * BB + c] * inv);
        int lbl = labels[n];             // uniform across wave
        tot += e;
        #pragma unroll
        for (int cc = 0; cc < NCLS; ++cc) accs[cc] += (cc == lbl) ? e : 0.0f;
    }
    __shared__ float red[4][64][NCLS + 1];
    #pragma unroll
    for (int cc = 0; cc < NCLS; ++cc) red[rg][l][cc] = accs[cc];
    red[rg][l][NCLS] = tot;
    __syncthreads();
    if (rg == 0) {
        #pragma unroll
        for (int cc = 0; cc < NCLS; ++cc) {
            float s = red[0][l][cc] + red[1][l][cc] + red[2][l][cc] + red[3][l][cc];
            atomicAdd(&ynum[c * NCLS + cc], s);
        }
        float st = red[0][l][NCLS] + red[1][l][NCLS] + red[2][l][NCLS] + red[3][l][NCLS];
        atomicAdd(&ydenom[c], st);
    }
}

__global__ void ystar_final(const float* __restrict__ ynum, const float* __restrict__ ydenom,
                            float* __restrict__ out) {
    int i = blockIdx.x * blockDim.x + threadIdx.x;
    if (i < BB * NCLS) out[i] = ynum[i] / ydenom[i / NCLS];
}

extern "C" void kernel_launch(void* const* d_in, const int* in_sizes, int n_in,
                              void* d_out, int out_size, void* d_ws, size_t ws_size,
                              hipStream_t stream) {
    const float* x     = (const float*)d_in[0];   // [512,512]
    const float* star  = (const float*)d_in[1];   // [4096,512]
    const float* from  = (const float*)d_in[2];   // [4096,512]
    const int*   label = (const int*)d_in[3];     // [4096]
    float* out = (float*)d_out;                   // [512,10]

    float* F = (float*)d_ws;
    float* dbuf   = F;                  // 2097152  (d / e / d2, reused)
    float* wpart  = F + 2097152;        // 2097152  (8 K-slabs of w partials)
    float* xt     = F + 4194304;        // 262144
    float* sn2    = F + 4456448;        // 4096
    float* fn2    = F + 4460544;        // 4096
    float* xb2    = F + 4464640;        // 512
    float* xt2    = F + 4465152;        // 512
    float* cs1    = F + 4465664;        // 512
    float* sumE   = F + 4466176;        // 512
    float* cs2    = F + 4466688;        // 512
    float* ynum   = F + 4467200;        // 5120
    float* ydenom = F + 4472320;        // 512
    int*   midx   = (int*)(F + 4472832);// 512

    init_kernel<<<20, 256, 0, stream>>>(cs1, sumE, cs2, ynum, ydenom, midx);
    row_sqnorm<<<NS, 64, 0, stream>>>(star, sn2);
    row_sqnorm<<<NS, 64, 0, stream>>>(from, fn2);
    row_sqnorm<<<BB, 64, 0, stream>>>(x, xb2);
    match_kernel<<<(NS * BB) / 256, 256, 0, stream>>>(x, star, midx);
    // d = sqdist(star, x): [4096, 512], + column sums
    gemm_abt_sq<<<dim3(NS / 64, BB / 64), 256, 0, stream>>>(star, x, sn2, xb2, dbuf, cs1);
    // e = exp(-T * d / colmean), + column sums of e
    exp_kernel<<<dim3(8, 8), 256, 0, stream>>>(dbuf, cs1, sumE);
    // w partials = from^T @ e (K split 8 ways)
    gemm_atb_part<<<dim3(8, 8, 8), 256, 0, stream>>>(from, dbuf, wpart);
    // xt = (w / sumE)^T with exact-match override
    xt_kernel<<<(DDIM * BB) / 256, 256, 0, stream>>>(wpart, sumE, midx, from, xt);
    row_sqnorm<<<BB, 64, 0, stream>>>(xt, xt2);
    // d2 = sqdist(from, xt): [4096, 512], + column sums
    gemm_abt_sq<<<dim3(NS / 64, BB / 64), 256, 0, stream>>>(from, xt, fn2, xt2, dbuf, cs2);
    // label bins
    ystar_partial<<<dim3(8, 8), 256, 0, stream>>>(dbuf, cs2, label, ynum, ydenom);
    ystar_final<<<20, 256, 0, stream>>>(ynum, ydenom, out);
}

// Round 3
// 78.750 us; speedup vs baseline: 2.8995x; 2.8995x over previous
//
#include <hip/hip_runtime.h>

#define TEMP 10.0f
#define NS 4096
#define BB 512
#define DDIM 512
#define NCLS 10

typedef short bf16x8 __attribute__((ext_vector_type(8)));
typedef float f32x4 __attribute__((ext_vector_type(4)));

__device__ inline short f2bf(float f) {
    unsigned u = __builtin_bit_cast(unsigned, f);
    u += 0x7FFFu + ((u >> 16) & 1u);      // round-to-nearest-even
    return (short)(u >> 16);
}
__device__ inline float bf2f(short h) {
    unsigned u = ((unsigned)(unsigned short)h) << 16;
    return __builtin_bit_cast(float, u);
}

// ---------------- init match sentinel ----------------
__global__ void init_midx(int* midx) {
    int t = blockIdx.x * 256 + threadIdx.x;
    if (t < BB) midx[t] = NS;
}

// ---------------- fp32 [rows][512] -> bf16 same layout + row sqnorms ----------------
__global__ __launch_bounds__(256)
void conv512(const float* __restrict__ in, short* __restrict__ outb,
             float* __restrict__ n2) {
    int row = blockIdx.x * 4 + (threadIdx.x >> 6);
    int l = threadIdx.x & 63;
    const float4* p = (const float4*)(in + (size_t)row * DDIM) + l * 2;
    float4 a = p[0], b = p[1];
    float s = a.x*a.x + a.y*a.y + a.z*a.z + a.w*a.w
            + b.x*b.x + b.y*b.y + b.z*b.z + b.w*b.w;
    bf16x8 h;
    h[0]=f2bf(a.x); h[1]=f2bf(a.y); h[2]=f2bf(a.z); h[3]=f2bf(a.w);
    h[4]=f2bf(b.x); h[5]=f2bf(b.y); h[6]=f2bf(b.z); h[7]=f2bf(b.w);
    *(bf16x8*)(outb + (size_t)row * DDIM + l * 8) = h;
    #pragma unroll
    for (int off = 32; off > 0; off >>= 1) s += __shfl_down(s, off);
    if (l == 0) n2[row] = s;
}

// ---------------- fp32 from[4096][512] -> bf16 fromT[512][4096] ----------------
__global__ __launch_bounds__(256)
void convT(const float* __restrict__ in, short* __restrict__ outb) {
    __shared__ short tile[64][72];
    int n0 = blockIdx.x * 64, d0 = blockIdx.y * 64;
    int t = threadIdx.x;
    int r = t >> 4, c4 = (t & 15) * 4;
    #pragma unroll
    for (int rr = 0; rr < 64; rr += 16) {
        float4 v = *(const float4*)(in + (size_t)(n0 + r + rr) * DDIM + d0 + c4);
        tile[r + rr][c4 + 0] = f2bf(v.x);
        tile[r + rr][c4 + 1] = f2bf(v.y);
        tile[r + rr][c4 + 2] = f2bf(v.z);
        tile[r + rr][c4 + 3] = f2bf(v.w);
    }
    __syncthreads();
    int dr = t >> 2, nco = (t & 3) * 16;
    short tmp[16];
    #pragma unroll
    for (int q = 0; q < 16; ++q) tmp[q] = tile[nco + q][dr];
    short* op = outb + (size_t)(d0 + dr) * NS + n0 + nco;
    *(bf16x8*)op       = *(bf16x8*)tmp;
    *(bf16x8*)(op + 8) = *(bf16x8*)(tmp + 8);
}

// ---------------- exact-match lookup ----------------
__global__ void match_kernel(const float* __restrict__ x, const float* __restrict__ star,
                             int* __restrict__ midx) {
    int i = blockIdx.x * blockDim.x + threadIdx.x;
    if (i >= NS * BB) return;
    int b = i & (BB - 1);
    int n = i >> 9;
    const float* xr = x + (size_t)b * DDIM;
    const float* sr = star + (size_t)n * DDIM;
    if (xr[0] != sr[0]) return;
    for (int k = 1; k < DDIM; ++k) if (xr[k] != sr[k]) return;
    atomicMin(&midx[b], n);
}

// ---------------- MFMA GEMM: C[m][n] = sum_k A[m][k]*B[n][k]  (bf16 in, f32 out) ----
// MODE 0: store raw acc (K-split partial).  MODE 1: store max(an2[m]+bn2[n]-2acc, 0).
#define BM 64
#define BN 128
#define BK 64
#define LDSP 72
template<int MODE>
__global__ __launch_bounds__(256)
void gemm_bt(const short* __restrict__ A, const short* __restrict__ B, int K,
             int kslab, int nt, const float* __restrict__ an2,
             const float* __restrict__ bn2, float* __restrict__ C, int ldc,
             size_t cstride) {
    __shared__ short As[2][BM][LDSP];   // 18432 B
    __shared__ short Bs[2][BN][LDSP];   // 36864 B
    int t = threadIdx.x;
    int m0 = blockIdx.x * BM;
    int n0 = blockIdx.y * BN;
    int kbase = blockIdx.z * kslab;
    float* Cp = C + (size_t)blockIdx.z * cstride;
    int wid = t >> 6, lane = t & 63;
    int wr = wid >> 1, wc = wid & 1;
    int lr = lane & 15, lk = lane >> 4;

    // staging map: A tile 64x64 shorts -> thread covers (row=t>>2, k=(t&3)*16..+16)
    //              B tile 128x64 shorts -> thread covers (row=t>>1, k=(t&1)*32..+32)
    int ar = t >> 2, ak = (t & 3) * 16;
    int br = t >> 1, bk = (t & 1) * 32;
    const short* Ag = A + (size_t)(m0 + ar) * K + kbase + ak;
    const short* Bg = B + (size_t)(n0 + br) * K + kbase + bk;

    f32x4 acc[2][4] = {};
    bf16x8 ra0 = *(const bf16x8*)Ag;
    bf16x8 ra1 = *(const bf16x8*)(Ag + 8);
    bf16x8 rb0 = *(const bf16x8*)Bg;
    bf16x8 rb1 = *(const bf16x8*)(Bg + 8);
    bf16x8 rb2 = *(const bf16x8*)(Bg + 16);
    bf16x8 rb3 = *(const bf16x8*)(Bg + 24);
    int cur = 0;
    *(bf16x8*)&As[0][ar][ak]      = ra0;
    *(bf16x8*)&As[0][ar][ak + 8]  = ra1;
    *(bf16x8*)&Bs[0][br][bk]      = rb0;
    *(bf16x8*)&Bs[0][br][bk + 8]  = rb1;
    *(bf16x8*)&Bs[0][br][bk + 16] = rb2;
    *(bf16x8*)&Bs[0][br][bk + 24] = rb3;

    for (int it = 0; it < nt; ++it) {
        __syncthreads();
        if (it + 1 < nt) {
            int ko = (it + 1) * BK;
            ra0 = *(const bf16x8*)(Ag + ko);
            ra1 = *(const bf16x8*)(Ag + ko + 8);
            rb0 = *(const bf16x8*)(Bg + ko);
            rb1 = *(const bf16x8*)(Bg + ko + 8);
            rb2 = *(const bf16x8*)(Bg + ko + 16);
            rb3 = *(const bf16x8*)(Bg + ko + 24);
        }
        #pragma unroll
        for (int ks = 0; ks < 2; ++ks) {
            int k0 = ks * 32 + lk * 8;
            bf16x8 af[2], bfr[4];
            #pragma unroll
            for (int i = 0; i < 2; ++i)
                af[i] = *(const bf16x8*)&As[cur][wr * 32 + i * 16 + lr][k0];
            #pragma unroll
            for (int j = 0; j < 4; ++j)
                bfr[j] = *(const bf16x8*)&Bs[cur][wc * 64 + j * 16 + lr][k0];
            #pragma unroll
            for (int i = 0; i < 2; ++i)
                #pragma unroll
                for (int j = 0; j < 4; ++j)
                    acc[i][j] = __builtin_amdgcn_mfma_f32_16x16x32_bf16(
                        af[i], bfr[j], acc[i][j], 0, 0, 0);
        }
        if (it + 1 < nt) {
            cur ^= 1;
            *(bf16x8*)&As[cur][ar][ak]      = ra0;
            *(bf16x8*)&As[cur][ar][ak + 8]  = ra1;
            *(bf16x8*)&Bs[cur][br][bk]      = rb0;
            *(bf16x8*)&Bs[cur][br][bk + 8]  = rb1;
            *(bf16x8*)&Bs[cur][br][bk + 16] = rb2;
            *(bf16x8*)&Bs[cur][br][bk + 24] = rb3;
        }
    }
    #pragma unroll
    for (int i = 0; i < 2; ++i) {
        #pragma unroll
        for (int r = 0; r < 4; ++r) {
            int gm = m0 + wr * 32 + i * 16 + lk * 4 + r;
            float a2 = (MODE == 1) ? an2[gm] : 0.0f;
            #pragma unroll
            for (int j = 0; j < 4; ++j) {
                int gn = n0 + wc * 64 + j * 16 + lr;
                float v = acc[i][j][r];
                if (MODE == 1) v = fmaxf(a2 + bn2[gn] - 2.0f * v, 0.0f);
                Cp[(size_t)gm * ldc + gn] = v;
            }
        }
    }
}

// ---------------- block-wide sum helper ----------------
__device__ inline float block_sum(float s, float* red) {
    #pragma unroll
    for (int off = 32; off > 0; off >>= 1) s += __shfl_down(s, off);
    int wid = threadIdx.x >> 6;
    if ((threadIdx.x & 63) == 0) red[wid] = s;
    __syncthreads();
    float tot = red[0] + red[1] + red[2] + red[3];
    __syncthreads();
    return tot;
}

// ---------------- e = exp(-T*d/rowmean), row of dT[b][:] -> bf16 eT + sumE ----------
__global__ __launch_bounds__(256)
void exp_rows(const float* __restrict__ dT, short* __restrict__ eT,
              float* __restrict__ sumE) {
    __shared__ float red[4];
    int b = blockIdx.x;
    int t = threadIdx.x;
    const float* row = dT + (size_t)b * NS;
    float4 v[4];
    float s = 0.f;
    #pragma unroll
    for (int q = 0; q < 4; ++q) {
        v[q] = *(const float4*)(row + t * 16 + q * 4);
        s += v[q].x + v[q].y + v[q].z + v[q].w;
    }
    float tot = block_sum(s, red);
    float scale = -TEMP * (float)NS / tot;
    float se = 0.f;
    bf16x8 h0, h1;
    #pragma unroll
    for (int q = 0; q < 4; ++q) {
        #pragma unroll
        for (int e = 0; e < 4; ++e) {
            float ev = __expf(v[q][e] * scale);
            short hh = f2bf(ev);
            se += bf2f(hh);
            if (q < 2) h0[q * 4 + e] = hh; else h1[(q - 2) * 4 + e] = hh;
        }
    }
    short* op = eT + (size_t)b * NS + t * 16;
    *(bf16x8*)op       = h0;
    *(bf16x8*)(op + 8) = h1;
    float setot = block_sum(se, red);
    if (t == 0) sumE[b] = setot;
}

// ---------------- xt[b][d] = sum_s wpart / sumE (or matched row) -> bf16 + norm ----
__global__ __launch_bounds__(256)
void xt_fin(const float* __restrict__ wpart, const float* __restrict__ sumE,
            const int* __restrict__ midx, const float* __restrict__ fromf,
            short* __restrict__ xtb, float* __restrict__ xtn2) {
    __shared__ float red[4];
    int b = blockIdx.x;
    int t = threadIdx.x;
    int d = t * 2;
    int mi = midx[b];
    float inv = 1.0f / sumE[b];
    float v0 = 0.f, v1 = 0.f;
    #pragma unroll
    for (int sl = 0; sl < 8; ++sl) {
        float2 p = *(const float2*)(wpart + (size_t)sl * (BB * DDIM) + (size_t)b * DDIM + d);
        v0 += p.x; v1 += p.y;
    }
    v0 *= inv; v1 *= inv;
    if (mi < NS) {
        v0 = fromf[(size_t)mi * DDIM + d];
        v1 = fromf[(size_t)mi * DDIM + d + 1];
    }
    xtb[(size_t)b * DDIM + d]     = f2bf(v0);
    xtb[(size_t)b * DDIM + d + 1] = f2bf(v1);
    float tot = block_sum(v0 * v0 + v1 * v1, red);
    if (t == 0) xtn2[b] = tot;
}

// ---------------- y_star row: softmax-weighted one-hot average ----------------
__global__ __launch_bounds__(256)
void ystar(const float* __restrict__ d2T, const int* __restrict__ labels,
           float* __restrict__ out) {
    __shared__ float red[4];
    __shared__ float cred[NCLS + 1][4];
    int b = blockIdx.x;
    int t = threadIdx.x;
    const float* row = d2T + (size_t)b * NS;
    float4 v[4];
    float s = 0.f;
    #pragma unroll
    for (int q = 0; q < 4; ++q) {
        v[q] = *(const float4*)(row + t * 16 + q * 4);
        s += v[q].x + v[q].y + v[q].z + v[q].w;
    }
    float tot = block_sum(s, red);
    float scale = -TEMP * (float)NS / tot;
    float accs[NCLS] = {};
    float te = 0.f;
    #pragma unroll
    for (int q = 0; q < 4; ++q) {
        int4 lb = *(const int4*)(labels + t * 16 + q * 4);
        int lbl[4] = {lb.x, lb.y, lb.z, lb.w};
        #pragma unroll
        for (int e = 0; e < 4; ++e) {
            float ev = __expf(v[q][e] * scale);
            te += ev;
            #pragma unroll
            for (int c = 0; c < NCLS; ++c) accs[c] += (lbl[e] == c) ? ev : 0.f;
        }
    }
    int wid = t >> 6, lane = t & 63;
    #pragma unroll
    for (int c = 0; c < NCLS + 1; ++c) {
        float sv = (c < NCLS) ? accs[c] : te;
        #pragma unroll
        for (int off = 32; off > 0; off >>= 1) sv += __shfl_down(sv, off);
        if (lane == 0) cred[c][wid] = sv;
    }
    __syncthreads();
    if (t < NCLS) {
        float num = cred[t][0] + cred[t][1] + cred[t][2] + cred[t][3];
        float den = cred[NCLS][0] + cred[NCLS][1] + cred[NCLS][2] + cred[NCLS][3];
        out[b * NCLS + t] = num / den;
    }
}

extern "C" void kernel_launch(void* const* d_in, const int* in_sizes, int n_in,
                              void* d_out, int out_size, void* d_ws, size_t ws_size,
                              hipStream_t stream) {
    const float* x     = (const float*)d_in[0];
    const float* star  = (const float*)d_in[1];
    const float* from  = (const float*)d_in[2];
    const int*   label = (const int*)d_in[3];
    float* out = (float*)d_out;

    float* F    = (float*)d_ws;
    float* Dbuf = F;                          // 8 MB: dT -> wpart -> d2T
    short* Sb   = (short*)(F + 2097152);      // 4 MB: star_b -> fromT_b -> from_b
    short* Eb   = (short*)(F + 3145728);      // 4 MB: eT_b
    short* Xb   = (short*)(F + 4194304);      // 0.5 MB: x_b
    short* XTb  = (short*)(F + 4325376);      // 0.5 MB: xt_b
    float* sn2  = F + 4456448;                // 4096
    float* fn2  = sn2 + 4096;                 // 4096
    float* xn2  = fn2 + 4096;                 // 512
    float* xtn2 = xn2 + 512;                  // 512
    float* sumE = xtn2 + 512;                 // 512
    int*   midx = (int*)(sumE + 512);         // 512

    init_midx<<<2, 256, 0, stream>>>(midx);
    conv512<<<NS / 4, 256, 0, stream>>>(star, Sb, sn2);
    conv512<<<BB / 4, 256, 0, stream>>>(x, Xb, xn2);
    match_kernel<<<(NS * BB) / 256, 256, 0, stream>>>(x, star, midx);
    // dT[b][n] = clamp(|x_b|^2 + |star_n|^2 - 2 x_b.star_n, 0)
    gemm_bt<1><<<dim3(BB / BM, NS / BN), 256, 0, stream>>>(
        Xb, Sb, DDIM, DDIM, DDIM / BK, xn2, sn2, Dbuf, NS, 0);
    convT<<<dim3(NS / 64, DDIM / 64), 256, 0, stream>>>(from, Sb);  // fromT_b
    exp_rows<<<BB, 256, 0, stream>>>(Dbuf, Eb, sumE);
    // wpart[z][b][d] = sum_{n in slab z} eT[b][n] * fromT[d][n]
    gemm_bt<0><<<dim3(BB / BM, DDIM / BN, 8), 256, 0, stream>>>(
        Eb, Sb, NS, NS / 8, (NS / 8) / BK, nullptr, nullptr, Dbuf, DDIM,
        (size_t)BB * DDIM);
    conv512<<<NS / 4, 256, 0, stream>>>(from, Sb, fn2);             // from_b
    xt_fin<<<BB, 256, 0, stream>>>(Dbuf, sumE, midx, from, XTb, xtn2);
    // d2T[b][n] = clamp(|xt_b|^2 + |from_n|^2 - 2 xt_b.from_n, 0)
    gemm_bt<1><<<dim3(BB / BM, NS / BN), 256, 0, stream>>>(
        XTb, Sb, DDIM, DDIM, DDIM / BK, xtn2, fn2, Dbuf, NS, 0);
    ystar<<<BB, 256, 0, stream>>>(Dbuf, label, out);
}